// Round 14
// baseline (329.983 us; speedup 1.0000x reference)
//
#include <hip/hip_runtime.h>
#include <cstdint>
#include <cstddef>

#define B_   2
#define S_   2048
#define H_   2048
#define NH_  16
#define HD_  128
#define MM_  (B_ * S_)          /* 4096 rows of x */
#define K_   H_                 /* 2048 reduction dim for projections */
#define SCALE_F 0.08838834764831845f
#define LOG2E_F 1.4426950408889634f
#define QSCALE_F (SCALE_F * LOG2E_F)

typedef __bf16 bf16_t;
typedef __attribute__((ext_vector_type(8))) __bf16 bf16x8;
typedef __attribute__((ext_vector_type(4))) __bf16 bf16x4;
typedef __attribute__((ext_vector_type(4))) float  f32x4;
typedef __attribute__((ext_vector_type(4))) float  floatx4;

static __device__ __forceinline__ f32x4 mfma_16x16x32(bf16x8 a, bf16x8 b, f32x4 c) {
  return __builtin_amdgcn_mfma_f32_16x16x32_bf16(a, b, c, 0, 0, 0);
}

static __device__ __forceinline__ void gl2lds16(const bf16_t* g, bf16_t* l) {
  __builtin_amdgcn_global_load_lds(
      (const __attribute__((address_space(1))) void*)g,
      (__attribute__((address_space(3))) void*)l, 16, 0, 0);
}

static __device__ __forceinline__ float exp2_hw(float x) {
  float r;
  asm("v_exp_f32 %0, %1" : "=v"(r) : "v"(x));
  return r;
}

// ------------------------------------------- fp32->bf16, 6 slices, one launch
__global__ void cvt6_f32_bf16(const float* __restrict__ x,
                              const float* __restrict__ w0, const float* __restrict__ w1,
                              const float* __restrict__ w2, const float* __restrict__ w3,
                              bf16_t* xo, bf16_t* o0, bf16_t* o1, bf16_t* o2, bf16_t* o3,
                              int n8) {
  const int yy = blockIdx.y;
  const float* in;
  bf16_t* out;
  if (yy == 0)      { in = x;                      out = xo; }
  else if (yy == 1) { in = x + (size_t)H_ * H_;    out = xo + (size_t)H_ * H_; }
  else if (yy == 2) { in = w0; out = o0; }
  else if (yy == 3) { in = w1; out = o1; }
  else if (yy == 4) { in = w2; out = o2; }
  else              { in = w3; out = o3; }
  int i = blockIdx.x * blockDim.x + threadIdx.x;
  const int stride = gridDim.x * blockDim.x;
  for (; i < n8; i += stride) {
    const floatx4* p = (const floatx4*)(in + (size_t)i * 8);
    floatx4 a = p[0], b = p[1];
    bf16x8 o;
    o[0] = (bf16_t)a.x; o[1] = (bf16_t)a.y; o[2] = (bf16_t)a.z; o[3] = (bf16_t)a.w;
    o[4] = (bf16_t)b.x; o[5] = (bf16_t)b.y; o[6] = (bf16_t)b.z; o[7] = (bf16_t)b.w;
    *(bf16x8*)(out + (size_t)i * 8) = o;
  }
}

// ------------------------------------------------------- GEMM C = A * B^T + b
// m97 structure. R14: per-XCD COLUMN OWNERSHIP mapping — each XCD (lin&7)
// owns NCOLS/8 nc-columns for the whole kernel: B-slice (3MB QKV / 1MB Oproj)
// stays L2-resident; consecutive j share one A-slice (0.5MB): window 3.5MB
// < 4MB L2. A streams once per XCD (L3-served after first toucher).
template <int MODE, int NCOLS>
__global__ __launch_bounds__(256) void gemm_bt(
    const bf16_t* __restrict__ A,
    const bf16_t* __restrict__ W0, const bf16_t* __restrict__ W1, const bf16_t* __restrict__ W2,
    const float* __restrict__ bias0, const float* __restrict__ bias1, const float* __restrict__ bias2,
    bf16_t* __restrict__ dq, bf16_t* __restrict__ dk, bf16_t* __restrict__ dv,
    float* __restrict__ outf)
{
  __shared__ __align__(16) bf16_t Ash[128 * 32];
  __shared__ __align__(16) bf16_t Bsh[128 * 32];

  const int t = threadIdx.x;
  const int lane = t & 63;
  const int wid  = t >> 6;
  const int wm = wid >> 1, wn = wid & 1;

  // per-XCD column ownership: lin = (tm*NCPX + nc_local)*8 + xcd (bijective)
  const int lin = blockIdx.x;
  const int xcd = lin & 7;
  const int j   = lin >> 3;
  constexpr int NCPX = NCOLS / 8;
  const int nc  = xcd * NCPX + (j % NCPX);
  const int tm  = j / NCPX;
  const int bm  = tm * 128;

  int bn;
  int wsel = 0;
  const bf16_t* Bw;
  const float*  bias;
  bf16_t* dsth = nullptr;
  if constexpr (MODE == 0) {
    wsel = nc >> 4;
    bn   = (nc & 15) * 128;
    Bw   = (wsel == 0) ? W0 : ((wsel == 1) ? W1 : W2);
    bias = (wsel == 0) ? bias0 : ((wsel == 1) ? bias1 : bias2);
    dsth = (wsel == 0) ? dq : ((wsel == 1) ? dk : dv);
  } else {
    bn = nc * 128;
    Bw = W0; bias = bias0;
  }

  const bf16_t* gA = A  + (size_t)(bm + (t >> 2)) * K_ + (t & 3) * 8;
  const bf16_t* gB = Bw + (size_t)(bn + (t >> 2)) * K_ + (t & 3) * 8;
  bf16_t* lA = Ash + wid * 512;
  bf16_t* lB = Bsh + wid * 512;

  f32x4 acc[4][4] = {};

  #pragma unroll 1
  for (int k0 = 0; k0 < K_; k0 += 32) {
    gl2lds16(gA + k0,                    lA);
    gl2lds16(gA + k0 + (size_t)64 * K_,  lA + 2048);
    gl2lds16(gB + k0,                    lB);
    gl2lds16(gB + k0 + (size_t)64 * K_,  lB + 2048);
    __syncthreads();

    bf16x8 af[4], bfr[4];
    #pragma unroll
    for (int i = 0; i < 4; ++i) {
      af[i]  = *(const bf16x8*)&Ash[(wm * 64 + i * 16 + (lane & 15)) * 32 + (lane >> 4) * 8];
      bfr[i] = *(const bf16x8*)&Bsh[(wn * 64 + i * 16 + (lane & 15)) * 32 + (lane >> 4) * 8];
    }
    __builtin_amdgcn_s_setprio(1);
    #pragma unroll
    for (int i = 0; i < 4; ++i)
      #pragma unroll
      for (int j2 = 0; j2 < 4; ++j2)
        acc[i][j2] = mfma_16x16x32(af[i], bfr[j2], acc[i][j2]);
    __builtin_amdgcn_s_setprio(0);
    __syncthreads();
  }

  const int row0 = bm + wm * 64 + (lane >> 4) * 4;
  const int col0 = bn + wn * 64 + (lane & 15);
  #pragma unroll
  for (int j2 = 0; j2 < 4; ++j2) {
    const int col = col0 + j2 * 16;
    const float bv = bias[col];
    #pragma unroll
    for (int i = 0; i < 4; ++i) {
      #pragma unroll
      for (int r = 0; r < 4; ++r) {
        const int row = row0 + i * 16 + r;
        float v = acc[i][j2][r] + bv;
        if constexpr (MODE == 0) {
          const int ss = row & (S_ - 1);
          const int dd = col & (HD_ - 1);
          const size_t bh = (size_t)((row >> 11) * NH_ + (col >> 7));
          if (wsel == 0) v *= QSCALE_F;
          size_t idx;
          if (wsel == 2) {
            // V frag-major: [bh][s>>6][d>>4][(s>>5)&1][(d&15)|(((s>>3)&3)<<4)][s&7]
            const size_t t1 = bh * 32 + (ss >> 6);
            const size_t t2 = t1 * 8 + (dd >> 4);
            const size_t t3 = t2 * 2 + ((ss >> 5) & 1);
            const size_t ln = (size_t)((dd & 15) | (((ss >> 3) & 3) << 4));
            idx = (t3 * 64 + ln) * 8 + (size_t)(ss & 7);
          } else {
            // Q/K frag-major: [bh][s>>4][d>>5][(s&15)|(((d>>3)&3)<<4)][d&7]
            const size_t t1 = bh * 128 + (ss >> 4);
            const size_t t2 = t1 * 4 + (dd >> 5);
            const size_t ln = (size_t)((ss & 15) | (((dd >> 3) & 3) << 4));
            idx = (t2 * 64 + ln) * 8 + (size_t)(dd & 7);
          }
          dsth[idx] = (bf16_t)v;
        } else {
          outf[(size_t)row * H_ + col] = v;
        }
      }
    }
  }
}

// ------------------------------------------------------------ flash attention
// R13-verified: swapped QK^T (lane owns one q-row) — softmax = 15 in-lane fmax
// + 2 shfl; P packs to b64 writes; PV = mfma(V^T, P^T) -> ctx^T b64 writeout.
// 128-thr blocks (2 waves x 32 q), grid 1024, LDS 40KB, 4 blocks/CU.
#define KVB 64
#define NT_ (S_ / KVB)
#define TILE_E 8192

__global__ __launch_bounds__(128, 2) void attn_kernel(
    const bf16_t* __restrict__ Qf, const bf16_t* __restrict__ Kf,
    const bf16_t* __restrict__ Vf, const float* __restrict__ mask,
    bf16_t* __restrict__ ctx)
{
  __shared__ __align__(16) bf16_t Klds[TILE_E];        // 16KB
  __shared__ __align__(16) bf16_t Vlds[TILE_E];        // 16KB
  __shared__ __align__(16) bf16_t Plds[2][2048];       // 8KB: per-wave P^T frags

  const int t = threadIdx.x;        // 0..127
  const int lane = t & 63;
  const int wid  = t >> 6;          // 0..1
  const int g    = lane >> 4;       // 0..3

  const int orig = blockIdx.x;
  const int wg = (orig & 7) * 128 + (orig >> 3);   // XCD swizzle (1024 % 8 == 0)
  const int qt = wg & 31;           // 32 q-tiles of 64 rows per head
  const int bh = wg >> 5;
  const int b  = bh >> 4;
  const int h  = bh & 15;
  const int q0 = qt * 64 + wid * 32;   // this wave's 32 q-rows

  const bf16_t* Kh0 = Kf + (size_t)bh * (NT_ * TILE_E);
  const bf16_t* Vh0 = Vf + (size_t)bh * (NT_ * TILE_E);
  const float*  mg  = mask + (size_t)b * S_;

  // Q frags (B-operand; frag-major layout identical for A/B): [bh][qb][ks][lane][8]
  const bf16_t* Qt = Qf + (((size_t)bh * 128 + (q0 >> 4)) * 4) * 512;
  bf16x8 qf[2][4];
  #pragma unroll
  for (int mh = 0; mh < 2; ++mh)
    #pragma unroll
    for (int ks = 0; ks < 4; ++ks)
      qf[mh][ks] = *(const bf16x8*)&Qt[((mh * 4 + ks) * 64 + lane) * 8];

  f32x4 acc[2][8] = {};             // ctx^T: [mh][ds], col=q=lane&15, row=d
  float m_run[2] = {-INFINITY, -INFINITY};
  float l_run[2] = {0.0f, 0.0f};

  char* Pw = (char*)&Plds[wid][0];

  // stage K+V tile (16 x 16B chunks per thread, linear frag-major copy)
  auto stage = [&](int it) {
    const bf16_t* Ksrc = Kh0 + (size_t)it * TILE_E;
    const bf16_t* Vsrc = Vh0 + (size_t)it * TILE_E;
    #pragma unroll
    for (int i = 0; i < 8; ++i) {
      const int base = (i * 128 + wid * 64) * 8;   // wave-uniform elem base
      gl2lds16(Ksrc + base + lane * 8, &Klds[base]);
      gl2lds16(Vsrc + base + lane * 8, &Vlds[base]);
    }
  };

  #pragma unroll 1
  for (int it = 0; it < NT_; ++it) {
    stage(it);

    // mask: per lane kv = ns*16 + g*4 + r -> one float4 per ns
    const int kv0 = it * KVB;
    floatx4 mv[4];
    #pragma unroll
    for (int ns = 0; ns < 4; ++ns)
      mv[ns] = *(const floatx4*)&mg[kv0 + ns * 16 + g * 4];

    __syncthreads();   // staged K/V ready (drains vmcnt)

    // ---- S^T = K Q^T : A=K frag, B=Q frag. D: col=q(lane&15), row=kv(g*4+r)
    f32x4 sacc[2][4] = {};
    #pragma unroll
    for (int ns = 0; ns < 4; ++ns) {
      #pragma unroll
      for (int ks = 0; ks < 4; ++ks) {
        const bf16x8 kf = *(const bf16x8*)&Klds[((ns * 4 + ks) * 64 + lane) * 8];
        __builtin_amdgcn_s_setprio(1);
        sacc[0][ns] = mfma_16x16x32(kf, qf[0][ks], sacc[0][ns]);
        sacc[1][ns] = mfma_16x16x32(kf, qf[1][ks], sacc[1][ns]);
        __builtin_amdgcn_s_setprio(0);
      }
    }

    // ---- softmax: each lane owns one q-row per mh (16 kv in-lane + 2 shfl)
    float tmax[2];
    #pragma unroll
    for (int mh = 0; mh < 2; ++mh) {
      float tm = -INFINITY;
      #pragma unroll
      for (int ns = 0; ns < 4; ++ns)
        #pragma unroll
        for (int r = 0; r < 4; ++r) {
          sacc[mh][ns][r] += mv[ns][r];
          tm = fmaxf(tm, sacc[mh][ns][r]);
        }
      tm = fmaxf(tm, __shfl_xor(tm, 16));
      tm = fmaxf(tm, __shfl_xor(tm, 32));
      tmax[mh] = tm;
    }

    // defer-max (T13): rescale only when a row max grew by > 8 (exact math)
    const bool small = (tmax[0] <= m_run[0] + 8.0f) && (tmax[1] <= m_run[1] + 8.0f);
    if (!__all(small)) {
      #pragma unroll
      for (int mh = 0; mh < 2; ++mh) {
        const float mnew = fmaxf(m_run[mh], tmax[mh]);
        const float scl  = exp2_hw(m_run[mh] - mnew);
        m_run[mh] = mnew;
        l_run[mh] *= scl;
        #pragma unroll
        for (int ds = 0; ds < 8; ++ds)
          #pragma unroll
          for (int r = 0; r < 4; ++r)
            acc[mh][ds][r] *= scl;
      }
    }

    // ---- P = exp2(S - m); 4 r-values pack into ONE b64 LDS write (B-frag row)
    float rs[2] = {0.0f, 0.0f};
    #pragma unroll
    for (int mh = 0; mh < 2; ++mh) {
      #pragma unroll
      for (int ns = 0; ns < 4; ++ns) {
        bf16x4 pk;
        #pragma unroll
        for (int r = 0; r < 4; ++r) {
          const float p = exp2_hw(sacc[mh][ns][r] - m_run[mh]);
          rs[mh] += p;
          pk[r] = (bf16_t)p;
        }
        const int L = (lane & 15) | ((((ns & 1) << 1) | (g >> 1)) << 4);
        const int byte = mh * 2048 + ((ns >> 1) << 10) + L * 16 + (g & 1) * 8;
        *(bf16x4*)(Pw + byte) = pk;
      }
    }

    // ---- P^T B-frags (same wave wrote them; lgkm wait auto-inserted)
    bf16x8 pf[2][2];
    #pragma unroll
    for (int mh = 0; mh < 2; ++mh)
      #pragma unroll
      for (int ks2 = 0; ks2 < 2; ++ks2)
        pf[mh][ks2] = *(const bf16x8*)(Pw + mh * 2048 + ks2 * 1024 + lane * 16);

    // ---- ctx^T += V^T P^T : A=V^T frag (stored bytes), B=P^T frag
    #pragma unroll
    for (int ds = 0; ds < 8; ++ds) {
      const bf16x8 vf0 = *(const bf16x8*)&Vlds[((ds * 2 + 0) * 64 + lane) * 8];
      const bf16x8 vf1 = *(const bf16x8*)&Vlds[((ds * 2 + 1) * 64 + lane) * 8];
      __builtin_amdgcn_s_setprio(1);
      #pragma unroll
      for (int mh = 0; mh < 2; ++mh) {
        acc[mh][ds] = mfma_16x16x32(vf0, pf[mh][0], acc[mh][ds]);
        acc[mh][ds] = mfma_16x16x32(vf1, pf[mh][1], acc[mh][ds]);
      }
      __builtin_amdgcn_s_setprio(0);
    }

    // ---- deferred sum-reduce (2 shuffles, hides under PV tail)
    #pragma unroll
    for (int mh = 0; mh < 2; ++mh) {
      rs[mh] += __shfl_xor(rs[mh], 16);
      rs[mh] += __shfl_xor(rs[mh], 32);
      l_run[mh] += rs[mh];
    }

    __syncthreads();   // all waves done with K/V before next stage overwrites
  }

  // writeout: q = q0 + mh*16 + (lane&15); d = ds*16 + g*4 + r (r packs to b64)
  #pragma unroll
  for (int mh = 0; mh < 2; ++mh) {
    const int q = q0 + mh * 16 + (lane & 15);
    const float inv = 1.0f / l_run[mh];
    #pragma unroll
    for (int ds = 0; ds < 8; ++ds) {
      bf16x4 o;
      #pragma unroll
      for (int r = 0; r < 4; ++r)
        o[r] = (bf16_t)(acc[mh][ds][r] * inv);
      *(bf16x4*)&ctx[((size_t)(b * S_ + q)) * H_ + h * HD_ + ds * 16 + g * 4] = o;
    }
  }
}

// ---------------------------------------------------------------------- host
extern "C" void kernel_launch(void* const* d_in, const int* in_sizes, int n_in,
                              void* d_out, int out_size, void* d_ws, size_t ws_size,
                              hipStream_t stream) {
  (void)in_sizes; (void)n_in; (void)out_size; (void)ws_size;
  const float* x    = (const float*)d_in[0];
  const float* mask = (const float*)d_in[1];
  const float* Wq   = (const float*)d_in[2];
  const float* bq   = (const float*)d_in[3];
  const float* Wk   = (const float*)d_in[4];
  const float* bk   = (const float*)d_in[5];
  const float* Wv   = (const float*)d_in[6];
  const float* bv   = (const float*)d_in[7];
  const float* Wo   = (const float*)d_in[8];
  const float* bo   = (const float*)d_in[9];
  float* out = (float*)d_out;

  const size_t nX = (size_t)MM_ * H_;
  const size_t nW = (size_t)H_ * H_;

  bf16_t* xbf = (bf16_t*)d_ws;
  bf16_t* wqb = xbf + nX;
  bf16_t* wkb = wqb + nW;
  bf16_t* wvb = wkb + nW;
  bf16_t* wob = wvb + nW;
  bf16_t* qf  = wob + nW;   // frag-major Q
  bf16_t* kf  = qf + nX;    // frag-major K
  bf16_t* vf  = kf + nX;    // frag-major V
  bf16_t* cxb = vf + nX;

  cvt6_f32_bf16<<<dim3(512, 6), 256, 0, stream>>>(
      x, Wq, Wk, Wv, Wo, xbf, wqb, wkb, wvb, wob, (int)(nW / 8));

  gemm_bt<0, 48><<<32 * 48, 256, 0, stream>>>(
      xbf, wqb, wkb, wvb, bq, bk, bv, qf, kf, vf, nullptr);

  attn_kernel<<<1024, 128, 0, stream>>>(qf, kf, vf, mask, cxb);

  gemm_bt<1, 16><<<32 * 16, 256, 0, stream>>>(
      cxb, wob, nullptr, nullptr, bo, nullptr, nullptr, nullptr, nullptr, nullptr, out);
}

// Round 15
// 279.881 us; speedup vs baseline: 1.1790x; 1.1790x over previous
//
#include <hip/hip_runtime.h>
#include <cstdint>
#include <cstddef>

#define B_   2
#define S_   2048
#define H_   2048
#define NH_  16
#define HD_  128
#define MM_  (B_ * S_)          /* 4096 rows of x */
#define K_   H_                 /* 2048 reduction dim for projections */
#define SCALE_F 0.08838834764831845f
#define LOG2E_F 1.4426950408889634f
#define QSCALE_F (SCALE_F * LOG2E_F)

typedef __bf16 bf16_t;
typedef __attribute__((ext_vector_type(8))) __bf16 bf16x8;
typedef __attribute__((ext_vector_type(4))) __bf16 bf16x4;
typedef __attribute__((ext_vector_type(4))) float  f32x4;
typedef __attribute__((ext_vector_type(4))) float  floatx4;

static __device__ __forceinline__ f32x4 mfma_16x16x32(bf16x8 a, bf16x8 b, f32x4 c) {
  return __builtin_amdgcn_mfma_f32_16x16x32_bf16(a, b, c, 0, 0, 0);
}

static __device__ __forceinline__ void gl2lds16(const bf16_t* g, bf16_t* l) {
  __builtin_amdgcn_global_load_lds(
      (const __attribute__((address_space(1))) void*)g,
      (__attribute__((address_space(3))) void*)l, 16, 0, 0);
}

static __device__ __forceinline__ float exp2_hw(float x) {
  float r;
  asm("v_exp_f32 %0, %1" : "=v"(r) : "v"(x));
  return r;
}

// ------------------------------------------- fp32->bf16, 6 slices, one launch
__global__ void cvt6_f32_bf16(const float* __restrict__ x,
                              const float* __restrict__ w0, const float* __restrict__ w1,
                              const float* __restrict__ w2, const float* __restrict__ w3,
                              bf16_t* xo, bf16_t* o0, bf16_t* o1, bf16_t* o2, bf16_t* o3,
                              int n8) {
  const int yy = blockIdx.y;
  const float* in;
  bf16_t* out;
  if (yy == 0)      { in = x;                      out = xo; }
  else if (yy == 1) { in = x + (size_t)H_ * H_;    out = xo + (size_t)H_ * H_; }
  else if (yy == 2) { in = w0; out = o0; }
  else if (yy == 3) { in = w1; out = o1; }
  else if (yy == 4) { in = w2; out = o2; }
  else              { in = w3; out = o3; }
  int i = blockIdx.x * blockDim.x + threadIdx.x;
  const int stride = gridDim.x * blockDim.x;
  for (; i < n8; i += stride) {
    const floatx4* p = (const floatx4*)(in + (size_t)i * 8);
    floatx4 a = p[0], b = p[1];
    bf16x8 o;
    o[0] = (bf16_t)a.x; o[1] = (bf16_t)a.y; o[2] = (bf16_t)a.z; o[3] = (bf16_t)a.w;
    o[4] = (bf16_t)b.x; o[5] = (bf16_t)b.y; o[6] = (bf16_t)b.z; o[7] = (bf16_t)b.w;
    *(bf16x8*)(out + (size_t)i * 8) = o;
  }
}

// ------------------------------------------------------- GEMM C = A * B^T + b
// R15: R13's rect XCD mapping (reverted from R14) + BK=64 with the R6-verified
// XOR swizzle (source chunk g=(c&7)^(R&7), read chunk cc^(R&7) -> 0 bank
// conflicts, measured). 32 K-iterations (was 64): half the barrier drains,
// conflict-free ds_read_b128. LDS 32KB, ~3 blocks/CU.
template <int MODE, int NCOLS>
__global__ __launch_bounds__(256) void gemm_bt(
    const bf16_t* __restrict__ A,
    const bf16_t* __restrict__ W0, const bf16_t* __restrict__ W1, const bf16_t* __restrict__ W2,
    const float* __restrict__ bias0, const float* __restrict__ bias1, const float* __restrict__ bias2,
    bf16_t* __restrict__ dq, bf16_t* __restrict__ dk, bf16_t* __restrict__ dv,
    float* __restrict__ outf)
{
  __shared__ __align__(16) bf16_t Ash[128 * 64];   // 16 KB
  __shared__ __align__(16) bf16_t Bsh[128 * 64];   // 16 KB

  const int t = threadIdx.x;
  const int lane = t & 63;
  const int wid  = t >> 6;
  const int wm = wid >> 1, wn = wid & 1;

  // R13-verified rect mapping: rect r_ = xcd*(NCOLS/8)+sr covers 8tm x 4nc
  const int lin = blockIdx.x;
  const int xcd = lin & 7;
  const int loc = lin >> 3;
  const int sr  = loc >> 5;
  const int l   = loc & 31;
  const int r_  = xcd * (NCOLS / 8) + sr;
  const int tm  = (r_ & 3) * 8 + (l & 7);
  const int nc  = (r_ >> 2) * 4 + (l >> 3);
  const int bm  = tm * 128;

  int bn;
  int wsel = 0;
  const bf16_t* Bw;
  const float*  bias;
  bf16_t* dsth = nullptr;
  if constexpr (MODE == 0) {
    wsel = nc >> 4;
    bn   = (nc & 15) * 128;
    Bw   = (wsel == 0) ? W0 : ((wsel == 1) ? W1 : W2);
    bias = (wsel == 0) ? bias0 : ((wsel == 1) ? bias1 : bias2);
    dsth = (wsel == 0) ? dq : ((wsel == 1) ? dk : dv);
  } else {
    bn = nc * 128;
    Bw = W0; bias = bias0;
  }

  const bf16_t* gA = A  + (size_t)bm * K_;
  const bf16_t* gB = Bw + (size_t)bn * K_;

  f32x4 acc[4][4] = {};

  #pragma unroll 1
  for (int k0 = 0; k0 < K_; k0 += 64) {
    // stage 128x64 A and B tiles: chunk c = j*256 + t; row = c>>3;
    // source col chunk g = (c&7) ^ (row&7)  (inverse swizzle, R6-verified);
    // LDS dest linear (wave-uniform base + lane*16).
    #pragma unroll
    for (int j = 0; j < 4; ++j) {
      const int c = j * 256 + t;
      const int R = c >> 3;
      const int g = (c & 7) ^ (R & 7);
      bf16_t* la = Ash + (j * 256 + wid * 64) * 8;
      bf16_t* lb = Bsh + (j * 256 + wid * 64) * 8;
      gl2lds16(gA + (size_t)R * K_ + k0 + g * 8, la);
      gl2lds16(gB + (size_t)R * K_ + k0 + g * 8, lb);
    }
    __syncthreads();

    // swizzled conflict-free frag reads: chunk = cc ^ (row&7)
    bf16x8 af[4][2], bfr[4][2];
    #pragma unroll
    for (int i = 0; i < 4; ++i)
      #pragma unroll
      for (int kk = 0; kk < 2; ++kk) {
        const int Ra = wm * 64 + i * 16 + (lane & 15);
        const int ca = (kk * 4 + (lane >> 4)) ^ (Ra & 7);
        af[i][kk] = *(const bf16x8*)&Ash[Ra * 64 + ca * 8];
        const int Rb = wn * 64 + i * 16 + (lane & 15);
        const int cb = (kk * 4 + (lane >> 4)) ^ (Rb & 7);
        bfr[i][kk] = *(const bf16x8*)&Bsh[Rb * 64 + cb * 8];
      }
    __builtin_amdgcn_s_setprio(1);
    #pragma unroll
    for (int kk = 0; kk < 2; ++kk)
      #pragma unroll
      for (int i = 0; i < 4; ++i)
        #pragma unroll
        for (int j2 = 0; j2 < 4; ++j2)
          acc[i][j2] = mfma_16x16x32(af[i][kk], bfr[j2][kk], acc[i][j2]);
    __builtin_amdgcn_s_setprio(0);
    __syncthreads();
  }

  // epilogue. C/D frag: col = lane&15, row = (lane>>4)*4 + r
  const int row0 = bm + wm * 64 + (lane >> 4) * 4;
  const int col0 = bn + wn * 64 + (lane & 15);
  #pragma unroll
  for (int j2 = 0; j2 < 4; ++j2) {
    const int col = col0 + j2 * 16;
    const float bv = bias[col];
    #pragma unroll
    for (int i = 0; i < 4; ++i) {
      #pragma unroll
      for (int r = 0; r < 4; ++r) {
        const int row = row0 + i * 16 + r;
        float v = acc[i][j2][r] + bv;
        if constexpr (MODE == 0) {
          const int ss = row & (S_ - 1);
          const int dd = col & (HD_ - 1);
          const size_t bh = (size_t)((row >> 11) * NH_ + (col >> 7));
          if (wsel == 0) v *= QSCALE_F;
          size_t idx;
          if (wsel == 2) {
            // V frag-major: [bh][s>>6][d>>4][(s>>5)&1][(d&15)|(((s>>3)&3)<<4)][s&7]
            const size_t t1 = bh * 32 + (ss >> 6);
            const size_t t2 = t1 * 8 + (dd >> 4);
            const size_t t3 = t2 * 2 + ((ss >> 5) & 1);
            const size_t ln = (size_t)((dd & 15) | (((ss >> 3) & 3) << 4));
            idx = (t3 * 64 + ln) * 8 + (size_t)(ss & 7);
          } else {
            // Q/K frag-major: [bh][s>>4][d>>5][(s&15)|(((d>>3)&3)<<4)][d&7]
            const size_t t1 = bh * 128 + (ss >> 4);
            const size_t t2 = t1 * 4 + (dd >> 5);
            const size_t ln = (size_t)((ss & 15) | (((dd >> 3) & 3) << 4));
            idx = (t2 * 64 + ln) * 8 + (size_t)(dd & 7);
          }
          dsth[idx] = (bf16_t)v;
        } else {
          outf[(size_t)row * H_ + col] = v;
        }
      }
    }
  }
}

// ------------------------------------------------------------ flash attention
// R13-verified: swapped QK^T (lane owns one q-row) — softmax = 15 in-lane fmax
// + 2 shfl; P packs to b64 writes; PV = mfma(V^T, P^T) -> ctx^T b64 writeout.
// 128-thr blocks (2 waves x 32 q), grid 1024, LDS 40KB, 4 blocks/CU.
#define KVB 64
#define NT_ (S_ / KVB)
#define TILE_E 8192

__global__ __launch_bounds__(128, 2) void attn_kernel(
    const bf16_t* __restrict__ Qf, const bf16_t* __restrict__ Kf,
    const bf16_t* __restrict__ Vf, const float* __restrict__ mask,
    bf16_t* __restrict__ ctx)
{
  __shared__ __align__(16) bf16_t Klds[TILE_E];        // 16KB
  __shared__ __align__(16) bf16_t Vlds[TILE_E];        // 16KB
  __shared__ __align__(16) bf16_t Plds[2][2048];       // 8KB: per-wave P^T frags

  const int t = threadIdx.x;        // 0..127
  const int lane = t & 63;
  const int wid  = t >> 6;          // 0..1
  const int g    = lane >> 4;       // 0..3

  const int orig = blockIdx.x;
  const int wg = (orig & 7) * 128 + (orig >> 3);   // XCD swizzle (1024 % 8 == 0)
  const int qt = wg & 31;           // 32 q-tiles of 64 rows per head
  const int bh = wg >> 5;
  const int b  = bh >> 4;
  const int h  = bh & 15;
  const int q0 = qt * 64 + wid * 32;   // this wave's 32 q-rows

  const bf16_t* Kh0 = Kf + (size_t)bh * (NT_ * TILE_E);
  const bf16_t* Vh0 = Vf + (size_t)bh * (NT_ * TILE_E);
  const float*  mg  = mask + (size_t)b * S_;

  // Q frags (B-operand; frag-major layout identical for A/B): [bh][qb][ks][lane][8]
  const bf16_t* Qt = Qf + (((size_t)bh * 128 + (q0 >> 4)) * 4) * 512;
  bf16x8 qf[2][4];
  #pragma unroll
  for (int mh = 0; mh < 2; ++mh)
    #pragma unroll
    for (int ks = 0; ks < 4; ++ks)
      qf[mh][ks] = *(const bf16x8*)&Qt[((mh * 4 + ks) * 64 + lane) * 8];

  f32x4 acc[2][8] = {};             // ctx^T: [mh][ds], col=q=lane&15, row=d
  float m_run[2] = {-INFINITY, -INFINITY};
  float l_run[2] = {0.0f, 0.0f};

  char* Pw = (char*)&Plds[wid][0];

  // stage K+V tile (16 x 16B chunks per thread, linear frag-major copy)
  auto stage = [&](int it) {
    const bf16_t* Ksrc = Kh0 + (size_t)it * TILE_E;
    const bf16_t* Vsrc = Vh0 + (size_t)it * TILE_E;
    #pragma unroll
    for (int i = 0; i < 8; ++i) {
      const int base = (i * 128 + wid * 64) * 8;   // wave-uniform elem base
      gl2lds16(Ksrc + base + lane * 8, &Klds[base]);
      gl2lds16(Vsrc + base + lane * 8, &Vlds[base]);
    }
  };

  #pragma unroll 1
  for (int it = 0; it < NT_; ++it) {
    stage(it);

    // mask: per lane kv = ns*16 + g*4 + r -> one float4 per ns
    const int kv0 = it * KVB;
    floatx4 mv[4];
    #pragma unroll
    for (int ns = 0; ns < 4; ++ns)
      mv[ns] = *(const floatx4*)&mg[kv0 + ns * 16 + g * 4];

    __syncthreads();   // staged K/V ready (drains vmcnt)

    // ---- S^T = K Q^T : A=K frag, B=Q frag. D: col=q(lane&15), row=kv(g*4+r)
    f32x4 sacc[2][4] = {};
    #pragma unroll
    for (int ns = 0; ns < 4; ++ns) {
      #pragma unroll
      for (int ks = 0; ks < 4; ++ks) {
        const bf16x8 kf = *(const bf16x8*)&Klds[((ns * 4 + ks) * 64 + lane) * 8];
        __builtin_amdgcn_s_setprio(1);
        sacc[0][ns] = mfma_16x16x32(kf, qf[0][ks], sacc[0][ns]);
        sacc[1][ns] = mfma_16x16x32(kf, qf[1][ks], sacc[1][ns]);
        __builtin_amdgcn_s_setprio(0);
      }
    }

    // ---- softmax: each lane owns one q-row per mh (16 kv in-lane + 2 shfl)
    float tmax[2];
    #pragma unroll
    for (int mh = 0; mh < 2; ++mh) {
      float tm = -INFINITY;
      #pragma unroll
      for (int ns = 0; ns < 4; ++ns)
        #pragma unroll
        for (int r = 0; r < 4; ++r) {
          sacc[mh][ns][r] += mv[ns][r];
          tm = fmaxf(tm, sacc[mh][ns][r]);
        }
      tm = fmaxf(tm, __shfl_xor(tm, 16));
      tm = fmaxf(tm, __shfl_xor(tm, 32));
      tmax[mh] = tm;
    }

    // defer-max (T13): rescale only when a row max grew by > 8 (exact math)
    const bool small = (tmax[0] <= m_run[0] + 8.0f) && (tmax[1] <= m_run[1] + 8.0f);
    if (!__all(small)) {
      #pragma unroll
      for (int mh = 0; mh < 2; ++mh) {
        const float mnew = fmaxf(m_run[mh], tmax[mh]);
        const float scl  = exp2_hw(m_run[mh] - mnew);
        m_run[mh] = mnew;
        l_run[mh] *= scl;
        #pragma unroll
        for (int ds = 0; ds < 8; ++ds)
          #pragma unroll
          for (int r = 0; r < 4; ++r)
            acc[mh][ds][r] *= scl;
      }
    }

    // ---- P = exp2(S - m); 4 r-values pack into ONE b64 LDS write (B-frag row)
    float rs[2] = {0.0f, 0.0f};
    #pragma unroll
    for (int mh = 0; mh < 2; ++mh) {
      #pragma unroll
      for (int ns = 0; ns < 4; ++ns) {
        bf16x4 pk;
        #pragma unroll
        for (int r = 0; r < 4; ++r) {
          const float p = exp2_hw(sacc[mh][ns][r] - m_run[mh]);
          rs[mh] += p;
          pk[r] = (bf16_t)p;
        }
        const int L = (lane & 15) | ((((ns & 1) << 1) | (g >> 1)) << 4);
        const int byte = mh * 2048 + ((ns >> 1) << 10) + L * 16 + (g & 1) * 8;
        *(bf16x4*)(Pw + byte) = pk;
      }
    }

    // ---- P^T B-frags (same wave wrote them; lgkm wait auto-inserted)
    bf16x8 pf[2][2];
    #pragma unroll
    for (int mh = 0; mh < 2; ++mh)
      #pragma unroll
      for (int ks2 = 0; ks2 < 2; ++ks2)
        pf[mh][ks2] = *(const bf16x8*)(Pw + mh * 2048 + ks2 * 1024 + lane * 16);

    // ---- ctx^T += V^T P^T : A=V^T frag (stored bytes), B=P^T frag
    #pragma unroll
    for (int ds = 0; ds < 8; ++ds) {
      const bf16x8 vf0 = *(const bf16x8*)&Vlds[((ds * 2 + 0) * 64 + lane) * 8];
      const bf16x8 vf1 = *(const bf16x8*)&Vlds[((ds * 2 + 1) * 64 + lane) * 8];
      __builtin_amdgcn_s_setprio(1);
      #pragma unroll
      for (int mh = 0; mh < 2; ++mh) {
        acc[mh][ds] = mfma_16x16x32(vf0, pf[mh][0], acc[mh][ds]);
        acc[mh][ds] = mfma_16x16x32(vf1, pf[mh][1], acc[mh][ds]);
      }
      __builtin_amdgcn_s_setprio(0);
    }

    // ---- deferred sum-reduce (2 shuffles, hides under PV tail)
    #pragma unroll
    for (int mh = 0; mh < 2; ++mh) {
      rs[mh] += __shfl_xor(rs[mh], 16);
      rs[mh] += __shfl_xor(rs[mh], 32);
      l_run[mh] += rs[mh];
    }

    __syncthreads();   // all waves done with K/V before next stage overwrites
  }

  // writeout: q = q0 + mh*16 + (lane&15); d = ds*16 + g*4 + r (r packs to b64)
  #pragma unroll
  for (int mh = 0; mh < 2; ++mh) {
    const int q = q0 + mh * 16 + (lane & 15);
    const float inv = 1.0f / l_run[mh];
    #pragma unroll
    for (int ds = 0; ds < 8; ++ds) {
      bf16x4 o;
      #pragma unroll
      for (int r = 0; r < 4; ++r)
        o[r] = (bf16_t)(acc[mh][ds][r] * inv);
      *(bf16x4*)&ctx[((size_t)(b * S_ + q)) * H_ + h * HD_ + ds * 16 + g * 4] = o;
    }
  }
}

// ---------------------------------------------------------------------- host
extern "C" void kernel_launch(void* const* d_in, const int* in_sizes, int n_in,
                              void* d_out, int out_size, void* d_ws, size_t ws_size,
                              hipStream_t stream) {
  (void)in_sizes; (void)n_in; (void)out_size; (void)ws_size;
  const float* x    = (const float*)d_in[0];
  const float* mask = (const float*)d_in[1];
  const float* Wq   = (const float*)d_in[2];
  const float* bq   = (const float*)d_in[3];
  const float* Wk   = (const float*)d_in[4];
  const float* bk   = (const float*)d_in[5];
  const float* Wv   = (const float*)d_in[6];
  const float* bv   = (const float*)d_in[7];
  const float* Wo   = (const float*)d_in[8];
  const float* bo   = (const float*)d_in[9];
  float* out = (float*)d_out;

  const size_t nX = (size_t)MM_ * H_;
  const size_t nW = (size_t)H_ * H_;

  bf16_t* xbf = (bf16_t*)d_ws;
  bf16_t* wqb = xbf + nX;
  bf16_t* wkb = wqb + nW;
  bf16_t* wvb = wkb + nW;
  bf16_t* wob = wvb + nW;
  bf16_t* qf  = wob + nW;   // frag-major Q
  bf16_t* kf  = qf + nX;    // frag-major K
  bf16_t* vf  = kf + nX;    // frag-major V
  bf16_t* cxb = vf + nX;

  cvt6_f32_bf16<<<dim3(512, 6), 256, 0, stream>>>(
      x, Wq, Wk, Wv, Wo, xbf, wqb, wkb, wvb, wob, (int)(nW / 8));

  gemm_bt<0, 48><<<32 * 48, 256, 0, stream>>>(
      xbf, wqb, wkb, wvb, bq, bk, bv, qf, kf, vf, nullptr);

  attn_kernel<<<1024, 128, 0, stream>>>(qf, kf, vf, mask, cxb);

  gemm_bt<1, 16><<<32 * 16, 256, 0, stream>>>(
      cxb, wob, nullptr, nullptr, bo, nullptr, nullptr, nullptr, nullptr, nullptr, out);
}